// Round 13
// baseline (1222.967 us; speedup 1.0000x reference)
//
#include <hip/hip_runtime.h>
#include <hip/hip_bf16.h>
#include <hip/hip_fp16.h>
#include <hip/hip_cooperative_groups.h>

namespace cg = cooperative_groups;

#define DD 64
#define EPSV 1e-5f
#define MGRID 768
#define MSTEPS 33   // covers N <= 768*4*33 = 101376

static __device__ __forceinline__ float fatomic_add(float* p, float v) {
#if defined(__HIP_DEVICE_COMPILE__)
    return unsafeAtomicAdd(p, v);
#else
    return 0.f;
#endif
}

static __device__ __forceinline__ float gelu_exact(float x) {
    return 0.5f * x * (1.0f + erff(x * 0.70710678118654752f));
}

// ---------------- CSR build ----------------
__global__ void k_hist(const int* __restrict__ dst, int* __restrict__ counts, int e) {
    int i = blockIdx.x * 256 + threadIdx.x;
    if (i < e) atomicAdd(&counts[dst[i]], 1);
}

__global__ __launch_bounds__(1024) void k_bsum(const int* __restrict__ counts,
                                               int* __restrict__ bsum, int n) {
    __shared__ int wsum[16];
    int t = threadIdx.x;
    int i = blockIdx.x * 1024 + t;
    int v = (i < n) ? counts[i] : 0;
    int lane = t & 63, wv = t >> 6;
    int x = v;
#pragma unroll
    for (int o = 1; o < 64; o <<= 1) x += __shfl_xor(x, o, 64);
    if (lane == 0) wsum[wv] = x;
    __syncthreads();
    if (t == 0) {
        int r = 0;
#pragma unroll
        for (int w = 0; w < 16; ++w) r += wsum[w];
        bsum[blockIdx.x] = r;
    }
}

__global__ __launch_bounds__(128) void k_bscan(int* __restrict__ bsum, int nb) {
    __shared__ int ws[2];
    int t = threadIdx.x;
    int lane = t & 63, wv = t >> 6;
    int v = (t < nb) ? bsum[t] : 0;
    int x = v;
#pragma unroll
    for (int o = 1; o < 64; o <<= 1) {
        int u = __shfl_up(x, o, 64);
        if (lane >= o) x += u;
    }
    if (lane == 63) ws[wv] = x;
    __syncthreads();
    int add = (wv == 1) ? ws[0] : 0;
    if (t < nb) bsum[t] = add + x - v;  // exclusive
}

__global__ __launch_bounds__(1024) void k_downsweep(const int* __restrict__ counts,
                                                    const int* __restrict__ bsum,
                                                    int* __restrict__ off,
                                                    float* __restrict__ dinv,
                                                    int* __restrict__ bcur,
                                                    int n, int etotal) {
    __shared__ int wsum[16];
    int t = threadIdx.x;
    int i = blockIdx.x * 1024 + t;
    int v = (i < n) ? counts[i] : 0;
    int lane = t & 63, wv = t >> 6;
    int x = v;
#pragma unroll
    for (int o = 1; o < 64; o <<= 1) {
        int u = __shfl_up(x, o, 64);
        if (lane >= o) x += u;
    }
    if (lane == 63) wsum[wv] = x;
    __syncthreads();
    if (t == 0) {
        int r = 0;
#pragma unroll
        for (int w = 0; w < 16; ++w) { int y = wsum[w]; wsum[w] = r; r += y; }
    }
    __syncthreads();
    if (i < n) {
        int excl = bsum[blockIdx.x] + wsum[wv] + x - v;
        off[i] = excl;
        dinv[i] = rsqrtf((float)v + 1.0f);  // +1 self-loop
        if ((i & 255) == 0) bcur[i >> 8] = excl;
        if (i == n - 1) off[n] = etotal;
    }
}

// ---------------- Pass A: LDS-staged bucket binning (256-node buckets) ----------------
#define ACHUNK 2048
#define NBMAX 400
__global__ __launch_bounds__(256) void k_binA(const int* __restrict__ src,
                                              const int* __restrict__ dst,
                                              int* __restrict__ ebuf,
                                              int* __restrict__ bcur,
                                              int e, int nbuck) {
    __shared__ int cnt[NBMAX], startb[NBMAX], posb[NBMAX], gbase[NBMAX];
    __shared__ int stage[ACHUNK];
    __shared__ unsigned short stb[ACHUNK];
    int t = threadIdx.x;
    for (int cbase = blockIdx.x * ACHUNK; cbase < e; cbase += gridDim.x * ACHUNK) {
        int cval = min(ACHUNK, e - cbase);
        for (int i = t; i < nbuck; i += 256) { cnt[i] = 0; posb[i] = 0; }
        __syncthreads();
        int eb[8], es[8];
#pragma unroll
        for (int k = 0; k < 8; ++k) {
            int i = t + k * 256;
            if (i < cval) {
                int s = src[cbase + i];
                int d = dst[cbase + i];
                eb[k] = d >> 8;
                es[k] = s | ((d & 255) << 24);
                atomicAdd(&cnt[eb[k]], 1);
            } else eb[k] = -1;
        }
        __syncthreads();
        if (t == 0) {
            int r = 0;
            for (int b2 = 0; b2 < nbuck; ++b2) { startb[b2] = r; r += cnt[b2]; }
        }
        __syncthreads();
        for (int i = t; i < nbuck; i += 256)
            if (cnt[i] > 0) gbase[i] = atomicAdd(&bcur[i], cnt[i]);
#pragma unroll
        for (int k = 0; k < 8; ++k)
            if (eb[k] >= 0) {
                int idx = startb[eb[k]] + atomicAdd(&posb[eb[k]], 1);
                stage[idx] = es[k];
                stb[idx] = (unsigned short)eb[k];
            }
        __syncthreads();
        for (int i = t; i < cval; i += 256) {
            int b2 = stb[i];
            ebuf[gbase[b2] + (i - startb[b2])] = stage[i];
        }
        __syncthreads();
    }
}

__global__ __launch_bounds__(256) void k_binB(const int* __restrict__ ebuf,
                                              const int* __restrict__ offs,
                                              int* __restrict__ csr, int n) {
    __shared__ int cur[256];
    int b = blockIdx.x;
    int base = b << 8;
    int nn = min(256, n - base);
    int t = threadIdx.x;
    if (t < nn) cur[t] = offs[base + t];
    __syncthreads();
    int e0 = offs[base], e1 = offs[base + nn];
    for (int i = e0 + t; i < e1; i += 256) {
        int packed = ebuf[i];
        int dl = ((unsigned)packed) >> 24;
        int pos = atomicAdd(&cur[dl], 1);
        csr[pos] = packed & 0x00FFFFFF;
    }
}

// ---------------- misc: bounds + mirror mA[i]=dinv*x[i] + zero row N in both mirrors ----------------
__global__ void k_misc(const float* __restrict__ x, const float* __restrict__ dinv,
                       __half* __restrict__ mA, __half* __restrict__ mB, int n,
                       float* __restrict__ gstats,
                       const int* __restrict__ batch, int* __restrict__ bnd, int g) {
    int i = blockIdx.x * 256 + threadIdx.x;
    if (blockIdx.x == 0 && threadIdx.x < 384) gstats[threadIdx.x] = 0.f;
    int total = n * 64;
    if (i < total) {
        mA[i] = __float2half_rn(x[i] * dinv[i >> 6]);
    } else if (i < total + 64) {
        mA[i] = __float2half_rn(0.f);
        mB[i] = __float2half_rn(0.f);
    }
    if (i < n) {
        int b = batch[i];
        if (i == 0)
            for (int q = 0; q <= b; ++q) bnd[q] = 0;
        else {
            int pb = batch[i - 1];
            for (int q = pb + 1; q <= b; ++q) bnd[q] = i;
        }
        if (i == n - 1)
            for (int q = b + 1; q <= g; ++q) bnd[q] = n;
    }
}

// ================= cooperative mega: 3x(gather[agg->LDS] + BN/LN/GELU) + pool + head =================
__global__ __launch_bounds__(256) void k_mega(
    const int* __restrict__ offs, const int* __restrict__ csr, const float* __restrict__ dinv,
    const uint4* __restrict__ mAv, const uint4* __restrict__ mBv,
    __half* __restrict__ mA, __half* __restrict__ mB,
    const float* __restrict__ convW, const float* __restrict__ convB,
    const float* __restrict__ bn_g, const float* __restrict__ bn_b,
    const float* __restrict__ ln_g, const float* __restrict__ ln_b,
    float* __restrict__ gstats, const int* __restrict__ bnd,
    const float* __restrict__ W1, const float* __restrict__ b1,
    const float* __restrict__ ln1g, const float* __restrict__ ln1b,
    const float* __restrict__ W2, const float* __restrict__ b2,
    const float* __restrict__ ln2g, const float* __restrict__ ln2b,
    const float* __restrict__ W3, const float* __restrict__ b3,
    float* __restrict__ out, int n, int g_total, int nzero) {
    cg::grid_group grid = cg::this_grid();
    __shared__ float smem[4096];                 // W tile / stats / pool+head scratch
    __shared__ float sAgg[MSTEPS * 4 * 64];      // per-block agg rows (33.8 KB)
    int t = threadIdx.x;
    int lane = t & 63, wv = t >> 6;
    int oct = lane >> 3, sub = lane & 7;
    int stride = gridDim.x * 4;

    for (int l = 0; l < 3; ++l) {
        const uint4* gin = (l == 1) ? mBv : mAv;
        __half* gout = (l == 1) ? mA : mB;
        const __half* resm = (const __half*)((l == 1) ? mB : mA);  // == gin
        float* gsum = gstats + l * 128;
        float* gsumsq = gsum + 64;
        // stage W
        for (int i = t; i < 4096; i += 256) smem[i] = convW[(size_t)l * 4096 + i];
        __syncthreads();
        float bias = convB[l * 64 + lane];
        float s = 0.f, sq = 0.f;
        for (int st = 0; st < MSTEPS; ++st) {
            int node = blockIdx.x * 4 + wv + st * stride;
            if (node >= n) break;
            int a = offs[node], b = offs[node + 1];
            float dd = dinv[node];
            uint4 vself = gin[(size_t)node * 8 + sub];
            float acc[8];
#pragma unroll
            for (int p = 0; p < 8; ++p) acc[p] = 0.f;
            for (int base = a; base < b; base += 64) {
                int rem = b - base;
                int cnt = rem < 64 ? rem : 64;
                int ent = nzero;
                if (lane < cnt) ent = csr[base + lane];
                for (int jj = 0; jj < cnt; jj += 8) {
                    int sn = __shfl(ent, jj + oct, 64);
                    uint4 v = gin[(size_t)sn * 8 + sub];
                    const __half2* h2 = reinterpret_cast<const __half2*>(&v);
#pragma unroll
                    for (int p = 0; p < 4; ++p) {
                        float2 f = __half22float2(h2[p]);
                        acc[2 * p]     += f.x;
                        acc[2 * p + 1] += f.y;
                    }
                }
            }
#pragma unroll
            for (int p = 0; p < 8; ++p) {
                acc[p] += __shfl_xor(acc[p], 8, 64);
                acc[p] += __shfl_xor(acc[p], 16, 64);
                acc[p] += __shfl_xor(acc[p], 32, 64);
            }
            {
                const __half2* h2 = reinterpret_cast<const __half2*>(&vself);
#pragma unroll
                for (int p = 0; p < 4; ++p) {
                    float2 f = __half22float2(h2[p]);
                    acc[2 * p]     = (acc[2 * p]     + f.x) * dd;
                    acc[2 * p + 1] = (acc[2 * p + 1] + f.y) * dd;
                }
            }
            float r0 = bias, r1 = 0.f, r2 = 0.f, r3 = 0.f;
#pragma unroll
            for (int c = 0; c < 64; c += 4) {
                r0 += __shfl(acc[(c + 0) & 7], (c + 0) >> 3, 64) * smem[(c + 0) * 64 + lane];
                r1 += __shfl(acc[(c + 1) & 7], (c + 1) >> 3, 64) * smem[(c + 1) * 64 + lane];
                r2 += __shfl(acc[(c + 2) & 7], (c + 2) >> 3, 64) * smem[(c + 2) * 64 + lane];
                r3 += __shfl(acc[(c + 3) & 7], (c + 3) >> 3, 64) * smem[(c + 3) * 64 + lane];
            }
            float r = (r0 + r1) + (r2 + r3);
            sAgg[(st * 4 + wv) * 64 + lane] = r;  // agg stays in LDS
            s += r;
            sq += r * r;
        }
        __syncthreads();  // W dead; reuse smem for stats
        smem[t] = s;
        smem[256 + t] = sq;
        __syncthreads();
        if (t < 64) {
            float fs = smem[t] + smem[t + 64] + smem[t + 128] + smem[t + 192];
            float fq = smem[256 + t] + smem[256 + t + 64] + smem[256 + t + 128] + smem[256 + t + 192];
            fatomic_add(&gsum[t], fs);
            fatomic_add(&gsumsq[t], fq);
        }
        grid.sync();
        // ---- BN + residual + LN + GELU -> mirror ----
        float invN = 1.0f / (float)n;
        float mu_c = gsum[lane] * invN;
        float var_c = gsumsq[lane] * invN - mu_c * mu_c;
        float bscale = rsqrtf(var_c + EPSV) * bn_g[l * 64 + lane];
        float bshift = bn_b[l * 64 + lane];
        float lg = ln_g[l * 64 + lane], lb = ln_b[l * 64 + lane];
        int has_res = (l > 0), scale_out = (l < 2);
        for (int st = 0; st < MSTEPS; ++st) {
            int node = blockIdx.x * 4 + wv + st * stride;
            if (node >= n) break;
            float dd = dinv[node];
            float xv = sAgg[(st * 4 + wv) * 64 + lane];
            float hb = (xv - mu_c) * bscale + bshift;
            if (has_res) hb += __half2float(resm[(size_t)node * 64 + lane]) * (1.0f / dd);
            float ssum = hb;
#pragma unroll
            for (int o = 32; o; o >>= 1) ssum += __shfl_xor(ssum, o, 64);
            float rmu = ssum * (1.f / 64.f);
            float d = hb - rmu;
            float vs = d * d;
#pragma unroll
            for (int o = 32; o; o >>= 1) vs += __shfl_xor(vs, o, 64);
            float rvar = vs * (1.f / 64.f);
            float ln = d * rsqrtf(rvar + EPSV) * lg + lb;
            float g = gelu_exact(ln);
            float outv = scale_out ? g * dd : g;
            gout[(size_t)node * 64 + lane] = __float2half_rn(outv);
        }
        grid.sync();
    }

    // ---- pool + head: blocks [0, g_total) ----
    if (blockIdx.x >= (unsigned)g_total) return;
    int g = blockIdx.x;
    int s0 = bnd[g], e0 = bnd[g + 1];
    float ps = 0.f, pm = -INFINITY;
    const __half* hf = (const __half*)mB;
    for (int i = s0 + wv; i < e0; i += 4) {
        float v = __half2float(hf[(size_t)i * 64 + lane]);
        ps += v;
        pm = fmaxf(pm, v);
    }
    __syncthreads();
    smem[t] = ps;
    smem[256 + t] = pm;
    __syncthreads();
    float* zl = smem + 512;
    float* h1 = smem + 704;
    float* red = smem + 832;
    if (t < 64) {
        float fs = smem[t] + smem[t + 64] + smem[t + 128] + smem[t + 192];
        float fm = fmaxf(fmaxf(smem[256 + t], smem[256 + t + 64]),
                         fmaxf(smem[256 + t + 128], smem[256 + t + 192]));
        float cntf = (float)(e0 - s0);
        if (e0 == s0) fm = 0.f;
        zl[t] = fs / fmaxf(cntf, 1.0f);
        zl[64 + t] = fm;
        zl[128 + t] = fs;
    }
    __syncthreads();
    float acc = 0.f;
    if (t < 128) {
        acc = b1[t];
        for (int k = 0; k < 192; ++k) acc += zl[k] * W1[k * 128 + t];
    }
    float ssum = acc;
#pragma unroll
    for (int o = 32; o; o >>= 1) ssum += __shfl_xor(ssum, o, 64);
    if (lane == 0 && wv < 2) red[wv] = ssum;
    __syncthreads();
    float mu = (red[0] + red[1]) * (1.f / 128.f);
    float d = acc - mu;
    float q = d * d;
#pragma unroll
    for (int o = 32; o; o >>= 1) q += __shfl_xor(q, o, 64);
    __syncthreads();
    if (lane == 0 && wv < 2) red[wv] = q;
    __syncthreads();
    float var = (red[0] + red[1]) * (1.f / 128.f);
    if (t < 128) {
        float ln = d * rsqrtf(var + EPSV) * ln1g[t] + ln1b[t];
        h1[t] = gelu_exact(ln);
    }
    __syncthreads();
    if (t < 64) {
        float acc2 = b2[t];
        for (int k = 0; k < 128; ++k) acc2 += h1[k] * W2[k * 64 + t];
        float s2 = acc2;
#pragma unroll
        for (int o = 32; o; o >>= 1) s2 += __shfl_xor(s2, o, 64);
        float mu2 = s2 * (1.f / 64.f);
        float d2 = acc2 - mu2;
        float q2 = d2 * d2;
#pragma unroll
        for (int o = 32; o; o >>= 1) q2 += __shfl_xor(q2, o, 64);
        float var2 = q2 * (1.f / 64.f);
        float l2 = d2 * rsqrtf(var2 + EPSV) * ln2g[t] + ln2b[t];
        float g2 = gelu_exact(l2);
        float p = g2 * W3[t];
#pragma unroll
        for (int o = 32; o; o >>= 1) p += __shfl_xor(p, o, 64);
        if (t == 0) out[g] = p + b3[0];
    }
}

// ================= fallback (proven R12 path) =================
__global__ __launch_bounds__(256) void k_gather_gemm(const int* __restrict__ off,
                                                     const int* __restrict__ csr,
                                                     const float* __restrict__ dinv,
                                                     const uint4* __restrict__ m16,
                                                     const float* __restrict__ W,
                                                     const float* __restrict__ convB,
                                                     float* __restrict__ agg,
                                                     float* __restrict__ gsum,
                                                     float* __restrict__ gsumsq,
                                                     int n, int nzero) {
    __shared__ float Wl[64 * 64];
    int t = threadIdx.x;
    for (int i = t; i < 64 * 64; i += 256) Wl[i] = W[i];
    int lane = t & 63, wv = t >> 6;
    int oct = lane >> 3, sub = lane & 7;
    float bias = convB[lane];
    float s = 0.f, sq = 0.f;
    __syncthreads();
    for (int node = blockIdx.x * 4 + wv; node < n; node += gridDim.x * 4) {
        int a = off[node], b = off[node + 1];
        float dd = dinv[node];
        uint4 vself = m16[(size_t)node * 8 + sub];
        float acc[8];
#pragma unroll
        for (int p = 0; p < 8; ++p) acc[p] = 0.f;
        for (int base = a; base < b; base += 64) {
            int rem = b - base;
            int cnt = rem < 64 ? rem : 64;
            int ent = nzero;
            if (lane < cnt) ent = csr[base + lane];
            for (int jj = 0; jj < cnt; jj += 8) {
                int sn = __shfl(ent, jj + oct, 64);
                uint4 v = m16[(size_t)sn * 8 + sub];
                const __half2* h2 = reinterpret_cast<const __half2*>(&v);
#pragma unroll
                for (int p = 0; p < 4; ++p) {
                    float2 f = __half22float2(h2[p]);
                    acc[2 * p]     += f.x;
                    acc[2 * p + 1] += f.y;
                }
            }
        }
#pragma unroll
        for (int p = 0; p < 8; ++p) {
            acc[p] += __shfl_xor(acc[p], 8, 64);
            acc[p] += __shfl_xor(acc[p], 16, 64);
            acc[p] += __shfl_xor(acc[p], 32, 64);
        }
        {
            const __half2* h2 = reinterpret_cast<const __half2*>(&vself);
#pragma unroll
            for (int p = 0; p < 4; ++p) {
                float2 f = __half22float2(h2[p]);
                acc[2 * p]     = (acc[2 * p]     + f.x) * dd;
                acc[2 * p + 1] = (acc[2 * p + 1] + f.y) * dd;
            }
        }
        float r0 = bias, r1 = 0.f, r2 = 0.f, r3 = 0.f;
#pragma unroll
        for (int c = 0; c < 64; c += 4) {
            r0 += __shfl(acc[(c + 0) & 7], (c + 0) >> 3, 64) * Wl[(c + 0) * 64 + lane];
            r1 += __shfl(acc[(c + 1) & 7], (c + 1) >> 3, 64) * Wl[(c + 1) * 64 + lane];
            r2 += __shfl(acc[(c + 2) & 7], (c + 2) >> 3, 64) * Wl[(c + 2) * 64 + lane];
            r3 += __shfl(acc[(c + 3) & 7], (c + 3) >> 3, 64) * Wl[(c + 3) * 64 + lane];
        }
        float r = (r0 + r1) + (r2 + r3);
        agg[(size_t)node * 64 + lane] = r;
        s += r;
        sq += r * r;
    }
    __shared__ float ls[256], lq[256];
    ls[t] = s;
    lq[t] = sq;
    __syncthreads();
    if (t < 64) {
        float fs = ls[t] + ls[t + 64] + ls[t + 128] + ls[t + 192];
        float fq = lq[t] + lq[t + 64] + lq[t + 128] + lq[t + 192];
        fatomic_add(&gsum[t], fs);
        fatomic_add(&gsumsq[t], fq);
    }
}

__global__ __launch_bounds__(256) void k_bn_ln_gelu(const float* __restrict__ agg,
                                                    const __half* __restrict__ m16res,
                                                    const float* __restrict__ gsum,
                                                    const float* __restrict__ gsumsq,
                                                    const float* __restrict__ dinv,
                                                    const float* __restrict__ bng,
                                                    const float* __restrict__ bnb,
                                                    const float* __restrict__ lng,
                                                    const float* __restrict__ lnb,
                                                    __half* __restrict__ m16out,
                                                    int n, int has_res, int scale_out) {
    int t = threadIdx.x;
    int lane = t & 63, wv = t >> 6;
    float invN = 1.0f / (float)n;
    float mu_c = gsum[lane] * invN;
    float var_c = gsumsq[lane] * invN - mu_c * mu_c;
    float bscale = rsqrtf(var_c + EPSV) * bng[lane];
    float bshift = bnb[lane];
    float lg = lng[lane], lb = lnb[lane];
    for (int r = blockIdx.x * 4 + wv; r < n; r += gridDim.x * 4) {
        float dd = dinv[r];
        float x = agg[(size_t)r * 64 + lane];
        float hb = (x - mu_c) * bscale + bshift;
        if (has_res) hb += __half2float(m16res[(size_t)r * 64 + lane]) * (1.0f / dd);
        float ssum = hb;
#pragma unroll
        for (int off = 32; off; off >>= 1) ssum += __shfl_xor(ssum, off, 64);
        float rmu = ssum * (1.f / 64.f);
        float d = hb - rmu;
        float vs = d * d;
#pragma unroll
        for (int off = 32; off; off >>= 1) vs += __shfl_xor(vs, off, 64);
        float rvar = vs * (1.f / 64.f);
        float ln = d * rsqrtf(rvar + EPSV) * lg + lb;
        float g = gelu_exact(ln);
        float outv = scale_out ? g * dd : g;
        m16out[(size_t)r * 64 + lane] = __float2half_rn(outv);
    }
}

__global__ __launch_bounds__(256) void k_pool_z(const __half* __restrict__ h,
                                                const int* __restrict__ bnd,
                                                float* __restrict__ z) {
    int g = blockIdx.x;
    int t = threadIdx.x;
    int lane = t & 63, wv = t >> 6;
    int s0 = bnd[g], e0 = bnd[g + 1];
    float s = 0.f, mx = -INFINITY;
    for (int i = s0 + wv; i < e0; i += 4) {
        float v = __half2float(h[(size_t)i * 64 + lane]);
        s += v;
        mx = fmaxf(mx, v);
    }
    __shared__ float ss[256], sm[256];
    ss[t] = s;
    sm[t] = mx;
    __syncthreads();
    if (t < 64) {
        float fs = ss[t] + ss[t + 64] + ss[t + 128] + ss[t + 192];
        float fm = fmaxf(fmaxf(sm[t], sm[t + 64]), fmaxf(sm[t + 128], sm[t + 192]));
        float cntf = (float)(e0 - s0);
        float mean = fs / fmaxf(cntf, 1.0f);
        if (e0 == s0) fm = 0.f;
        z[g * 192 + t] = mean;
        z[g * 192 + 64 + t] = fm;
        z[g * 192 + 128 + t] = fs;
    }
}

__global__ __launch_bounds__(128) void k_head(const float* __restrict__ z,
                                              const float* __restrict__ W1, const float* __restrict__ b1,
                                              const float* __restrict__ ln1g, const float* __restrict__ ln1b,
                                              const float* __restrict__ W2, const float* __restrict__ b2,
                                              const float* __restrict__ ln2g, const float* __restrict__ ln2b,
                                              const float* __restrict__ W3, const float* __restrict__ b3,
                                              float* __restrict__ out) {
    int g = blockIdx.x;
    int t = threadIdx.x;
    int lane = t & 63, wv = t >> 6;
    __shared__ float zl[192], h1[128], red[2];
    for (int i = t; i < 192; i += 128) zl[i] = z[g * 192 + i];
    __syncthreads();
    float acc = b1[t];
    for (int k = 0; k < 192; ++k) acc += zl[k] * W1[k * 128 + t];
    float s = acc;
#pragma unroll
    for (int off = 32; off; off >>= 1) s += __shfl_xor(s, off, 64);
    if (lane == 0) red[wv] = s;
    __syncthreads();
    float mu = (red[0] + red[1]) * (1.f / 128.f);
    float d = acc - mu;
    float q = d * d;
#pragma unroll
    for (int off = 32; off; off >>= 1) q += __shfl_xor(q, off, 64);
    __syncthreads();
    if (lane == 0) red[wv] = q;
    __syncthreads();
    float var = (red[0] + red[1]) * (1.f / 128.f);
    float ln = d * rsqrtf(var + EPSV) * ln1g[t] + ln1b[t];
    h1[t] = gelu_exact(ln);
    __syncthreads();
    if (t < 64) {
        float acc2 = b2[t];
        for (int k = 0; k < 128; ++k) acc2 += h1[k] * W2[k * 64 + t];
        float s2 = acc2;
#pragma unroll
        for (int off = 32; off; off >>= 1) s2 += __shfl_xor(s2, off, 64);
        float mu2 = s2 * (1.f / 64.f);
        float d2 = acc2 - mu2;
        float q2 = d2 * d2;
#pragma unroll
        for (int off = 32; off; off >>= 1) q2 += __shfl_xor(q2, off, 64);
        float var2 = q2 * (1.f / 64.f);
        float l2 = d2 * rsqrtf(var2 + EPSV) * ln2g[t] + ln2b[t];
        float g2 = gelu_exact(l2);
        float p = g2 * W3[t];
#pragma unroll
        for (int off = 32; off; off >>= 1) p += __shfl_xor(p, off, 64);
        if (t == 0) out[g] = p + b3[0];
    }
}

extern "C" void kernel_launch(void* const* d_in, const int* in_sizes, int n_in,
                              void* d_out, int out_size, void* d_ws, size_t ws_size,
                              hipStream_t stream) {
    const float* x      = (const float*)d_in[0];
    const int*   eidx   = (const int*)d_in[1];
    const int*   batch  = (const int*)d_in[2];
    const float* convW  = (const float*)d_in[3];
    const float* convB  = (const float*)d_in[4];
    const float* bn_g   = (const float*)d_in[5];
    const float* bn_b   = (const float*)d_in[6];
    const float* ln_g   = (const float*)d_in[7];
    const float* ln_b   = (const float*)d_in[8];
    const float* W1     = (const float*)d_in[9];
    const float* b1     = (const float*)d_in[10];
    const float* ln1g   = (const float*)d_in[11];
    const float* ln1b   = (const float*)d_in[12];
    const float* W2     = (const float*)d_in[13];
    const float* b2     = (const float*)d_in[14];
    const float* ln2g   = (const float*)d_in[15];
    const float* ln2b   = (const float*)d_in[16];
    const float* W3     = (const float*)d_in[17];
    const float* b3     = (const float*)d_in[18];
    float* out = (float*)d_out;

    const int N = in_sizes[0] / DD;
    const int E = in_sizes[1] / 2;
    const int G = out_size;
    const int* esrc = eidx;
    const int* edst = eidx + E;

    char* ws = (char*)d_ws;
    size_t off_b = 0;
    auto alloc = [&](size_t bytes) {
        size_t p = off_b;
        off_b = (off_b + bytes + 255) & ~(size_t)255;
        return (void*)(ws + p);
    };
    int*    offs   = (int*)alloc((size_t)(N + 1) * 4);
    float*  dinv   = (float*)alloc((size_t)N * 4);
    int*    csr    = (int*)alloc((size_t)E * 4);
    int*    ebuf   = (int*)alloc((size_t)E * 4);
    __half* m16A   = (__half*)alloc((size_t)(N + 1) * DD * 2);
    __half* m16B   = (__half*)alloc((size_t)(N + 1) * DD * 2);
    float*  aggbuf = (float*)alloc((size_t)N * DD * 4);
    float*  gstats = (float*)alloc(3 * 2 * DD * 4);
    int*    bnd    = (int*)alloc((size_t)(G + 1) * 4);
    int*    bsum   = (int*)alloc(((size_t)(N + 1023) / 1024) * 4);
    int*    bcur   = (int*)alloc(((size_t)(N + 255) / 256) * 4);
    int*   counts = (int*)aggbuf;
    float* z      = aggbuf;
    (void)ws_size; (void)n_in;

    const int nb = (N + 1023) / 1024;
    const int nbuck = (N + 255) / 256;

    // ---- CSR build (proven R12 path) ----
    hipMemsetAsync(counts, 0, (size_t)N * 4, stream);
    k_hist<<<(E + 255) / 256, 256, 0, stream>>>(edst, counts, E);
    k_bsum<<<nb, 1024, 0, stream>>>(counts, bsum, N);
    k_bscan<<<1, 128, 0, stream>>>(bsum, nb);
    k_downsweep<<<nb, 1024, 0, stream>>>(counts, bsum, offs, dinv, bcur, N, E);
    k_binA<<<(E + ACHUNK - 1) / ACHUNK, 256, 0, stream>>>(esrc, edst, ebuf, bcur, E, nbuck);
    k_binB<<<nbuck, 256, 0, stream>>>(ebuf, offs, csr, N);
    k_misc<<<((N + 1) * DD + 255) / 256, 256, 0, stream>>>(x, dinv, m16A, m16B, N, gstats, batch, bnd, G);

    bool can_coop = (N <= MGRID * 4 * MSTEPS) && (G <= MGRID) && (nbuck <= NBMAX);
    hipError_t err = hipErrorUnknown;
    if (can_coop) {
        const uint4* mAv = (const uint4*)m16A;
        const uint4* mBv = (const uint4*)m16B;
        int n_ = N, g_ = G, nz_ = N;
        void* args[] = {
            (void*)&offs, (void*)&csr, (void*)&dinv, (void*)&mAv, (void*)&mBv,
            (void*)&m16A, (void*)&m16B, (void*)&convW, (void*)&convB,
            (void*)&bn_g, (void*)&bn_b, (void*)&ln_g, (void*)&ln_b,
            (void*)&gstats, (void*)&bnd,
            (void*)&W1, (void*)&b1, (void*)&ln1g, (void*)&ln1b,
            (void*)&W2, (void*)&b2, (void*)&ln2g, (void*)&ln2b,
            (void*)&W3, (void*)&b3, (void*)&out, (void*)&n_, (void*)&g_, (void*)&nz_};
        err = hipLaunchCooperativeKernel((const void*)k_mega, dim3(MGRID), dim3(256),
                                         args, 0, stream);
    }
    if (err != hipSuccess) {
        // fallback: proven R12 sequence
        __half* gin[3]  = {m16A, m16B, m16A};
        __half* gout[3] = {m16B, m16A, m16B};
        for (int l = 0; l < 3; ++l) {
            float* gsum = gstats + l * 128;
            float* gsumsq = gsum + 64;
            k_gather_gemm<<<2048, 256, 0, stream>>>(offs, csr, dinv, (const uint4*)gin[l],
                                                    convW + (size_t)l * DD * DD, convB + l * DD,
                                                    aggbuf, gsum, gsumsq, N, N);
            k_bn_ln_gelu<<<2048, 256, 0, stream>>>(aggbuf, gin[l], gsum, gsumsq, dinv,
                                                   bn_g + l * DD, bn_b + l * DD,
                                                   ln_g + l * DD, ln_b + l * DD,
                                                   gout[l], N, l > 0 ? 1 : 0, l < 2 ? 1 : 0);
        }
        k_pool_z<<<G, 256, 0, stream>>>(m16B, bnd, z);
        k_head<<<G, 128, 0, stream>>>(z, W1, b1, ln1g, ln1b, W2, b2, ln2g, ln2b, W3, b3, out);
    }
}

// Round 14
// 660.773 us; speedup vs baseline: 1.8508x; 1.8508x over previous
//
#include <hip/hip_runtime.h>
#include <hip/hip_bf16.h>
#include <hip/hip_fp16.h>

#define DD 64
#define EPSV 1e-5f

static __device__ __forceinline__ float fatomic_add(float* p, float v) {
#if defined(__HIP_DEVICE_COMPILE__)
    return unsafeAtomicAdd(p, v);
#else
    return 0.f;
#endif
}

static __device__ __forceinline__ float gelu_exact(float x) {
    return 0.5f * x * (1.0f + erff(x * 0.70710678118654752f));
}

// ---------------- CSR build ----------------
__global__ void k_hist(const int* __restrict__ dst, int* __restrict__ counts, int e) {
    int i = blockIdx.x * 256 + threadIdx.x;
    if (i < e) atomicAdd(&counts[dst[i]], 1);
}

__global__ __launch_bounds__(1024) void k_bsum(const int* __restrict__ counts,
                                               int* __restrict__ bsum, int n) {
    __shared__ int wsum[16];
    int t = threadIdx.x;
    int i = blockIdx.x * 1024 + t;
    int v = (i < n) ? counts[i] : 0;
    int lane = t & 63, wv = t >> 6;
    int x = v;
#pragma unroll
    for (int o = 1; o < 64; o <<= 1) x += __shfl_xor(x, o, 64);
    if (lane == 0) wsum[wv] = x;
    __syncthreads();
    if (t == 0) {
        int r = 0;
#pragma unroll
        for (int w = 0; w < 16; ++w) r += wsum[w];
        bsum[blockIdx.x] = r;
    }
}

__global__ __launch_bounds__(128) void k_bscan(int* __restrict__ bsum, int nb) {
    __shared__ int ws[2];
    int t = threadIdx.x;
    int lane = t & 63, wv = t >> 6;
    int v = (t < nb) ? bsum[t] : 0;
    int x = v;
#pragma unroll
    for (int o = 1; o < 64; o <<= 1) {
        int u = __shfl_up(x, o, 64);
        if (lane >= o) x += u;
    }
    if (lane == 63) ws[wv] = x;
    __syncthreads();
    int add = (wv == 1) ? ws[0] : 0;
    if (t < nb) bsum[t] = add + x - v;  // exclusive
}

// downsweep also seeds bucket cursors: bcur[i>>8] = offs[i] at bucket starts
__global__ __launch_bounds__(1024) void k_downsweep(const int* __restrict__ counts,
                                                    const int* __restrict__ bsum,
                                                    int* __restrict__ off,
                                                    float* __restrict__ dinv,
                                                    int* __restrict__ bcur,
                                                    int n, int etotal) {
    __shared__ int wsum[16];
    int t = threadIdx.x;
    int i = blockIdx.x * 1024 + t;
    int v = (i < n) ? counts[i] : 0;
    int lane = t & 63, wv = t >> 6;
    int x = v;
#pragma unroll
    for (int o = 1; o < 64; o <<= 1) {
        int u = __shfl_up(x, o, 64);
        if (lane >= o) x += u;
    }
    if (lane == 63) wsum[wv] = x;
    __syncthreads();
    if (t == 0) {
        int r = 0;
#pragma unroll
        for (int w = 0; w < 16; ++w) { int y = wsum[w]; wsum[w] = r; r += y; }
    }
    __syncthreads();
    if (i < n) {
        int excl = bsum[blockIdx.x] + wsum[wv] + x - v;
        off[i] = excl;
        dinv[i] = rsqrtf((float)v + 1.0f);  // +1 self-loop
        if ((i & 255) == 0) bcur[i >> 8] = excl;  // bucket cursor seed
        if (i == n - 1) off[n] = etotal;
    }
}

// ---------------- Pass A: LDS-staged bucket binning (256-node buckets) ----------------
// ebuf entry: (dstLocal<<24) | src   (src < 2^24, dstLocal < 256)
#define ACHUNK 2048
#define NBMAX 400
__global__ __launch_bounds__(256) void k_binA(const int* __restrict__ src,
                                              const int* __restrict__ dst,
                                              int* __restrict__ ebuf,
                                              int* __restrict__ bcur,
                                              int e, int nbuck) {
    __shared__ int cnt[NBMAX], startb[NBMAX], posb[NBMAX], gbase[NBMAX];
    __shared__ int stage[ACHUNK];
    __shared__ unsigned short stb[ACHUNK];
    int t = threadIdx.x;
    for (int cbase = blockIdx.x * ACHUNK; cbase < e; cbase += gridDim.x * ACHUNK) {
        int cval = min(ACHUNK, e - cbase);
        for (int i = t; i < nbuck; i += 256) { cnt[i] = 0; posb[i] = 0; }
        __syncthreads();
        int eb[8], es[8];
#pragma unroll
        for (int k = 0; k < 8; ++k) {
            int i = t + k * 256;
            if (i < cval) {
                int s = src[cbase + i];
                int d = dst[cbase + i];
                eb[k] = d >> 8;
                es[k] = s | ((d & 255) << 24);
                atomicAdd(&cnt[eb[k]], 1);
            } else eb[k] = -1;
        }
        __syncthreads();
        if (t == 0) {
            int r = 0;
            for (int b2 = 0; b2 < nbuck; ++b2) { startb[b2] = r; r += cnt[b2]; }
        }
        __syncthreads();
        for (int i = t; i < nbuck; i += 256)
            if (cnt[i] > 0) gbase[i] = atomicAdd(&bcur[i], cnt[i]);
#pragma unroll
        for (int k = 0; k < 8; ++k)
            if (eb[k] >= 0) {
                int idx = startb[eb[k]] + atomicAdd(&posb[eb[k]], 1);
                stage[idx] = es[k];
                stb[idx] = (unsigned short)eb[k];
            }
        __syncthreads();
        for (int i = t; i < cval; i += 256) {
            int b2 = stb[i];
            ebuf[gbase[b2] + (i - startb[b2])] = stage[i];
        }
        __syncthreads();
    }
}

// ---------------- Pass B: within-bucket scatter to CSR (single block per bucket) ----------------
__global__ __launch_bounds__(256) void k_binB(const int* __restrict__ ebuf,
                                              const int* __restrict__ offs,
                                              int* __restrict__ csr, int n) {
    __shared__ int cur[256];
    int b = blockIdx.x;
    int base = b << 8;
    int nn = min(256, n - base);
    int t = threadIdx.x;
    if (t < nn) cur[t] = offs[base + t];
    __syncthreads();
    int e0 = offs[base], e1 = offs[base + nn];
    for (int i = e0 + t; i < e1; i += 256) {
        int packed = ebuf[i];
        int dl = ((unsigned)packed) >> 24;
        int pos = atomicAdd(&cur[dl], 1);
        csr[pos] = packed & 0x00FFFFFF;
    }
}

// ---------------- misc: bounds + mirror mA[i]=dinv*x[i] + zero row N in both mirrors ----------------
__global__ void k_misc(const float* __restrict__ x, const float* __restrict__ dinv,
                       __half* __restrict__ mA, __half* __restrict__ mB, int n,
                       float* __restrict__ gstats,
                       const int* __restrict__ batch, int* __restrict__ bnd, int g) {
    int i = blockIdx.x * 256 + threadIdx.x;
    if (blockIdx.x == 0 && threadIdx.x < 384) gstats[threadIdx.x] = 0.f;
    int total = n * 64;
    if (i < total) {
        mA[i] = __float2half_rn(x[i] * dinv[i >> 6]);
    } else if (i < total + 64) {
        mA[i] = __float2half_rn(0.f);  // dummy zero row at index n (gather tail identity)
        mB[i] = __float2half_rn(0.f);
    }
    if (i < n) {
        int b = batch[i];
        if (i == 0)
            for (int q = 0; q <= b; ++q) bnd[q] = 0;
        else {
            int pb = batch[i - 1];
            for (int q = pb + 1; q <= b; ++q) bnd[q] = i;
        }
        if (i == n - 1)
            for (int q = b + 1; q <= g; ++q) bnd[q] = n;
    }
}

// ---------------- fused: pre-scaled fp16 gather -> row GEMM -> BN col stats ----------------
// Operating point (confirmed from 4 directions): 64 VGPR, 8 edges in flight, 2048 blocks.
// agg[d,:] = (dinv[d]*(m16[d,:] + sum_e m16[src_e,:])) @ W + convB,  m16[i]=dinv[i]*h[i]
__global__ __launch_bounds__(256) void k_gather_gemm(const int* __restrict__ off,
                                                     const int* __restrict__ csr,
                                                     const float* __restrict__ dinv,
                                                     const uint4* __restrict__ m16,
                                                     const float* __restrict__ W,
                                                     const float* __restrict__ convB,
                                                     float* __restrict__ agg,
                                                     float* __restrict__ gsum,
                                                     float* __restrict__ gsumsq,
                                                     int n, int nzero) {
    __shared__ float Wl[64 * 64];
    int t = threadIdx.x;
    for (int i = t; i < 64 * 64; i += 256) Wl[i] = W[i];
    int lane = t & 63, wv = t >> 6;
    int oct = lane >> 3;   // which edge of an 8-group this lane gathers
    int sub = lane & 7;    // which 16B chunk (8 cols) of the row
    float bias = convB[lane];
    float s = 0.f, sq = 0.f;
    __syncthreads();
    for (int node = blockIdx.x * 4 + wv; node < n; node += gridDim.x * 4) {
        int a = off[node], b = off[node + 1];
        float dd = dinv[node];
        uint4 vself = m16[(size_t)node * 8 + sub];  // hoisted: in flight during edge loop
        float acc[8];
#pragma unroll
        for (int p = 0; p < 8; ++p) acc[p] = 0.f;
        for (int base = a; base < b; base += 64) {
            int rem = b - base;
            int cnt = rem < 64 ? rem : 64;
            int ent = nzero;  // tail lanes -> dummy zero row (adds 0)
            if (lane < cnt) ent = csr[base + lane];
            for (int jj = 0; jj < cnt; jj += 8) {
                int sn = __shfl(ent, jj + oct, 64);  // jj+oct <= 63 always
                uint4 v = m16[(size_t)sn * 8 + sub];
                const __half2* h2 = reinterpret_cast<const __half2*>(&v);
#pragma unroll
                for (int p = 0; p < 4; ++p) {
                    float2 f = __half22float2(h2[p]);
                    acc[2 * p]     += f.x;
                    acc[2 * p + 1] += f.y;
                }
            }
        }
        // reduce across octs: lanes with equal sub sum up
#pragma unroll
        for (int p = 0; p < 8; ++p) {
            acc[p] += __shfl_xor(acc[p], 8, 64);
            acc[p] += __shfl_xor(acc[p], 16, 64);
            acc[p] += __shfl_xor(acc[p], 32, 64);
        }
        // self term + outer dinv scale (cols 8*sub + p)
        {
            const __half2* h2 = reinterpret_cast<const __half2*>(&vself);
#pragma unroll
            for (int p = 0; p < 4; ++p) {
                float2 f = __half22float2(h2[p]);
                acc[2 * p]     = (acc[2 * p]     + f.x) * dd;
                acc[2 * p + 1] = (acc[2 * p + 1] + f.y) * dd;
            }
        }
        // row GEMM: column c's value is component (c&7) of lane (c>>3)
        float r0 = bias, r1 = 0.f, r2 = 0.f, r3 = 0.f;
#pragma unroll
        for (int c = 0; c < 64; c += 4) {
            r0 += __shfl(acc[(c + 0) & 7], (c + 0) >> 3, 64) * Wl[(c + 0) * 64 + lane];
            r1 += __shfl(acc[(c + 1) & 7], (c + 1) >> 3, 64) * Wl[(c + 1) * 64 + lane];
            r2 += __shfl(acc[(c + 2) & 7], (c + 2) >> 3, 64) * Wl[(c + 2) * 64 + lane];
            r3 += __shfl(acc[(c + 3) & 7], (c + 3) >> 3, 64) * Wl[(c + 3) * 64 + lane];
        }
        float r = (r0 + r1) + (r2 + r3);
        agg[(size_t)node * 64 + lane] = r;
        s += r;
        sq += r * r;
    }
    __shared__ float ls[256], lq[256];
    ls[t] = s;
    lq[t] = sq;
    __syncthreads();
    if (t < 64) {
        float fs = ls[t] + ls[t + 64] + ls[t + 128] + ls[t + 192];
        float fq = lq[t] + lq[t + 64] + lq[t + 128] + lq[t + 192];
        fatomic_add(&gsum[t], fs);
        fatomic_add(&gsumsq[t], fq);
    }
}

// ---------------- BN + residual(fp16 mirror) + LN + GELU -> fp16 mirror only ----------------
__global__ __launch_bounds__(256) void k_bn_ln_gelu(const float* __restrict__ agg,
                                                    const __half* __restrict__ m16res,
                                                    const float* __restrict__ gsum,
                                                    const float* __restrict__ gsumsq,
                                                    const float* __restrict__ dinv,
                                                    const float* __restrict__ bng,
                                                    const float* __restrict__ bnb,
                                                    const float* __restrict__ lng,
                                                    const float* __restrict__ lnb,
                                                    __half* __restrict__ m16out,
                                                    int n, int has_res, int scale_out) {
    int t = threadIdx.x;
    int lane = t & 63, wv = t >> 6;
    float invN = 1.0f / (float)n;
    float mu_c = gsum[lane] * invN;
    float var_c = gsumsq[lane] * invN - mu_c * mu_c;
    float bscale = rsqrtf(var_c + EPSV) * bng[lane];
    float bshift = bnb[lane];
    float lg = lng[lane], lb = lnb[lane];
    for (int r = blockIdx.x * 4 + wv; r < n; r += gridDim.x * 4) {
        float dd = dinv[r];
        float x = agg[(size_t)r * 64 + lane];
        float hb = (x - mu_c) * bscale + bshift;
        if (has_res) hb += __half2float(m16res[(size_t)r * 64 + lane]) * (1.0f / dd);
        float ssum = hb;
#pragma unroll
        for (int off = 32; off; off >>= 1) ssum += __shfl_xor(ssum, off, 64);
        float rmu = ssum * (1.f / 64.f);
        float d = hb - rmu;
        float vs = d * d;
#pragma unroll
        for (int off = 32; off; off >>= 1) vs += __shfl_xor(vs, off, 64);
        float rvar = vs * (1.f / 64.f);
        float ln = d * rsqrtf(rvar + EPSV) * lg + lb;
        float g = gelu_exact(ln);
        float outv = scale_out ? g * dd : g;
        m16out[(size_t)r * 64 + lane] = __float2half_rn(outv);
    }
}

// ---------------- pooling: one block per graph (4 waves split rows), fp16 h ----------------
__global__ __launch_bounds__(256) void k_pool_z(const __half* __restrict__ h,
                                                const int* __restrict__ bnd,
                                                float* __restrict__ z) {
    int g = blockIdx.x;
    int t = threadIdx.x;
    int lane = t & 63, wv = t >> 6;
    int s0 = bnd[g], e0 = bnd[g + 1];
    float s = 0.f, mx = -INFINITY;
    for (int i = s0 + wv; i < e0; i += 4) {
        float v = __half2float(h[(size_t)i * 64 + lane]);
        s += v;
        mx = fmaxf(mx, v);
    }
    __shared__ float ss[256], sm[256];
    ss[t] = s;
    sm[t] = mx;
    __syncthreads();
    if (t < 64) {
        float fs = ss[t] + ss[t + 64] + ss[t + 128] + ss[t + 192];
        float fm = fmaxf(fmaxf(sm[t], sm[t + 64]), fmaxf(sm[t + 128], sm[t + 192]));
        float cntf = (float)(e0 - s0);
        float mean = fs / fmaxf(cntf, 1.0f);
        if (e0 == s0) fm = 0.f;
        z[g * 192 + t] = mean;
        z[g * 192 + 64 + t] = fm;
        z[g * 192 + 128 + t] = fs;
    }
}

// ---------------- MLP head (one block per graph) ----------------
__global__ __launch_bounds__(128) void k_head(const float* __restrict__ z,
                                              const float* __restrict__ W1, const float* __restrict__ b1,
                                              const float* __restrict__ ln1g, const float* __restrict__ ln1b,
                                              const float* __restrict__ W2, const float* __restrict__ b2,
                                              const float* __restrict__ ln2g, const float* __restrict__ ln2b,
                                              const float* __restrict__ W3, const float* __restrict__ b3,
                                              float* __restrict__ out) {
    int g = blockIdx.x;
    int t = threadIdx.x;
    int lane = t & 63, wv = t >> 6;
    __shared__ float zl[192], h1[128], red[2];
    for (int i = t; i < 192; i += 128) zl[i] = z[g * 192 + i];
    __syncthreads();
    float acc = b1[t];
    for (int k = 0; k < 192; ++k) acc += zl[k] * W1[k * 128 + t];
    float s = acc;
#pragma unroll
    for (int off = 32; off; off >>= 1) s += __shfl_xor(s, off, 64);
    if (lane == 0) red[wv] = s;
    __syncthreads();
    float mu = (red[0] + red[1]) * (1.f / 128.f);
    float d = acc - mu;
    float q = d * d;
#pragma unroll
    for (int off = 32; off; off >>= 1) q += __shfl_xor(q, off, 64);
    __syncthreads();
    if (lane == 0) red[wv] = q;
    __syncthreads();
    float var = (red[0] + red[1]) * (1.f / 128.f);
    float ln = d * rsqrtf(var + EPSV) * ln1g[t] + ln1b[t];
    h1[t] = gelu_exact(ln);
    __syncthreads();
    if (t < 64) {
        float acc2 = b2[t];
        for (int k = 0; k < 128; ++k) acc2 += h1[k] * W2[k * 64 + t];
        float s2 = acc2;
#pragma unroll
        for (int off = 32; off; off >>= 1) s2 += __shfl_xor(s2, off, 64);
        float mu2 = s2 * (1.f / 64.f);
        float d2 = acc2 - mu2;
        float q2 = d2 * d2;
#pragma unroll
        for (int off = 32; off; off >>= 1) q2 += __shfl_xor(q2, off, 64);
        float var2 = q2 * (1.f / 64.f);
        float l2 = d2 * rsqrtf(var2 + EPSV) * ln2g[t] + ln2b[t];
        float g2 = gelu_exact(l2);
        float p = g2 * W3[t];
#pragma unroll
        for (int off = 32; off; off >>= 1) p += __shfl_xor(p, off, 64);
        if (t == 0) out[g] = p + b3[0];
    }
}

extern "C" void kernel_launch(void* const* d_in, const int* in_sizes, int n_in,
                              void* d_out, int out_size, void* d_ws, size_t ws_size,
                              hipStream_t stream) {
    const float* x      = (const float*)d_in[0];
    const int*   eidx   = (const int*)d_in[1];
    const int*   batch  = (const int*)d_in[2];
    const float* convW  = (const float*)d_in[3];
    const float* convB  = (const float*)d_in[4];
    const float* bn_g   = (const float*)d_in[5];
    const float* bn_b   = (const float*)d_in[6];
    const float* ln_g   = (const float*)d_in[7];
    const float* ln_b   = (const float*)d_in[8];
    const float* W1     = (const float*)d_in[9];
    const float* b1     = (const float*)d_in[10];
    const float* ln1g   = (const float*)d_in[11];
    const float* ln1b   = (const float*)d_in[12];
    const float* W2     = (const float*)d_in[13];
    const float* b2     = (const float*)d_in[14];
    const float* ln2g   = (const float*)d_in[15];
    const float* ln2b   = (const float*)d_in[16];
    const float* W3     = (const float*)d_in[17];
    const float* b3     = (const float*)d_in[18];
    float* out = (float*)d_out;

    const int N = in_sizes[0] / DD;
    const int E = in_sizes[1] / 2;
    const int G = out_size;
    const int* esrc = eidx;
    const int* edst = eidx + E;

    char* ws = (char*)d_ws;
    size_t off_b = 0;
    auto alloc = [&](size_t bytes) {
        size_t p = off_b;
        off_b = (off_b + bytes + 255) & ~(size_t)255;
        return (void*)(ws + p);
    };
    // layout total ~65 MB (< 77.6 MB proven safe):
    int*    offs   = (int*)alloc((size_t)(N + 1) * 4);
    float*  dinv   = (float*)alloc((size_t)N * 4);
    int*    csr    = (int*)alloc((size_t)E * 4);                 // src only
    int*    ebuf   = (int*)alloc((size_t)E * 4);                 // bucket-grouped packed edges
    __half* m16A   = (__half*)alloc((size_t)(N + 1) * DD * 2);   // +1 dummy zero row
    __half* m16B   = (__half*)alloc((size_t)(N + 1) * DD * 2);
    float*  aggbuf = (float*)alloc((size_t)N * DD * 4);          // single fp32 agg buffer
    float*  gstats = (float*)alloc(3 * 2 * DD * 4);              // 3 layers x (gsum|gsumsq)
    int*    bnd    = (int*)alloc((size_t)(G + 1) * 4);
    int*    bsum   = (int*)alloc(((size_t)(N + 1023) / 1024) * 4);
    int*    bcur   = (int*)alloc(((size_t)(N + 255) / 256) * 4);
    // aliases into dead regions of aggbuf:
    int*   counts = (int*)aggbuf;  // live only during CSR build (before L0 gather)
    float* z      = aggbuf;        // live only after L2 bn consumed aggbuf
    (void)ws_size; (void)n_in;

    const int nb = (N + 1023) / 1024;
    const int nbuck = (N + 255) / 256;

    // ---- CSR build (once per launch): hist -> scan -> two-pass binned fill ----
    hipMemsetAsync(counts, 0, (size_t)N * 4, stream);
    k_hist<<<(E + 255) / 256, 256, 0, stream>>>(edst, counts, E);
    k_bsum<<<nb, 1024, 0, stream>>>(counts, bsum, N);
    k_bscan<<<1, 128, 0, stream>>>(bsum, nb);
    k_downsweep<<<nb, 1024, 0, stream>>>(counts, bsum, offs, dinv, bcur, N, E);
    k_binA<<<(E + ACHUNK - 1) / ACHUNK, 256, 0, stream>>>(esrc, edst, ebuf, bcur, E, nbuck);
    k_binB<<<nbuck, 256, 0, stream>>>(ebuf, offs, csr, N);
    k_misc<<<((N + 1) * DD + 255) / 256, 256, 0, stream>>>(x, dinv, m16A, m16B, N, gstats, batch, bnd, G);

    // mirror rotation:
    //   L0: gather m16A -> agg; bn: agg -> m16B (scaled)          [res: none]
    //   L1: gather m16B -> agg; bn: agg + res(m16B) -> m16A (scaled)
    //   L2: gather m16A -> agg; bn: agg + res(m16A) -> m16B (unscaled, feeds pool)
    __half* gin[3]  = {m16A, m16B, m16A};
    __half* gout[3] = {m16B, m16A, m16B};

    for (int l = 0; l < 3; ++l) {
        float* gsum = gstats + l * 128;
        float* gsumsq = gsum + 64;
        k_gather_gemm<<<2048, 256, 0, stream>>>(offs, csr, dinv, (const uint4*)gin[l],
                                                convW + (size_t)l * DD * DD, convB + l * DD,
                                                aggbuf, gsum, gsumsq, N, N);
        k_bn_ln_gelu<<<2048, 256, 0, stream>>>(aggbuf, gin[l], gsum, gsumsq, dinv,
                                               bn_g + l * DD, bn_b + l * DD,
                                               ln_g + l * DD, ln_b + l * DD,
                                               gout[l], N, l > 0 ? 1 : 0, l < 2 ? 1 : 0);
    }

    k_pool_z<<<G, 256, 0, stream>>>(m16B, bnd, z);
    k_head<<<G, 128, 0, stream>>>(z, W1, b1, ln1g, ln1b, W2, b2, ln2g, ln2b, W3, b3, out);
}

// Round 15
// 651.835 us; speedup vs baseline: 1.8762x; 1.0137x over previous
//
#include <hip/hip_runtime.h>
#include <hip/hip_bf16.h>
#include <hip/hip_fp16.h>

#define DD 64
#define EPSV 1e-5f

static __device__ __forceinline__ float fatomic_add(float* p, float v) {
#if defined(__HIP_DEVICE_COMPILE__)
    return unsafeAtomicAdd(p, v);
#else
    return 0.f;
#endif
}

static __device__ __forceinline__ float gelu_exact(float x) {
    return 0.5f * x * (1.0f + erff(x * 0.70710678118654752f));
}

// ---------------- CSR build ----------------
__global__ void k_hist(const int* __restrict__ dst, int* __restrict__ counts, int e) {
    int i = blockIdx.x * 256 + threadIdx.x;
    if (i < e) atomicAdd(&counts[dst[i]], 1);
}

__global__ __launch_bounds__(1024) void k_bsum(const int* __restrict__ counts,
                                               int* __restrict__ bsum, int n) {
    __shared__ int wsum[16];
    int t = threadIdx.x;
    int i = blockIdx.x * 1024 + t;
    int v = (i < n) ? counts[i] : 0;
    int lane = t & 63, wv = t >> 6;
    int x = v;
#pragma unroll
    for (int o = 1; o < 64; o <<= 1) x += __shfl_xor(x, o, 64);
    if (lane == 0) wsum[wv] = x;
    __syncthreads();
    if (t == 0) {
        int r = 0;
#pragma unroll
        for (int w = 0; w < 16; ++w) r += wsum[w];
        bsum[blockIdx.x] = r;
    }
}

__global__ __launch_bounds__(128) void k_bscan(int* __restrict__ bsum, int nb) {
    __shared__ int ws[2];
    int t = threadIdx.x;
    int lane = t & 63, wv = t >> 6;
    int v = (t < nb) ? bsum[t] : 0;
    int x = v;
#pragma unroll
    for (int o = 1; o < 64; o <<= 1) {
        int u = __shfl_up(x, o, 64);
        if (lane >= o) x += u;
    }
    if (lane == 63) ws[wv] = x;
    __syncthreads();
    int add = (wv == 1) ? ws[0] : 0;
    if (t < nb) bsum[t] = add + x - v;  // exclusive
}

// downsweep also seeds bucket cursors: bcur[i>>8] = offs[i] at bucket starts
__global__ __launch_bounds__(1024) void k_downsweep(const int* __restrict__ counts,
                                                    const int* __restrict__ bsum,
                                                    int* __restrict__ off,
                                                    float* __restrict__ dinv,
                                                    int* __restrict__ bcur,
                                                    int n, int etotal) {
    __shared__ int wsum[16];
    int t = threadIdx.x;
    int i = blockIdx.x * 1024 + t;
    int v = (i < n) ? counts[i] : 0;
    int lane = t & 63, wv = t >> 6;
    int x = v;
#pragma unroll
    for (int o = 1; o < 64; o <<= 1) {
        int u = __shfl_up(x, o, 64);
        if (lane >= o) x += u;
    }
    if (lane == 63) wsum[wv] = x;
    __syncthreads();
    if (t == 0) {
        int r = 0;
#pragma unroll
        for (int w = 0; w < 16; ++w) { int y = wsum[w]; wsum[w] = r; r += y; }
    }
    __syncthreads();
    if (i < n) {
        int excl = bsum[blockIdx.x] + wsum[wv] + x - v;
        off[i] = excl;
        dinv[i] = rsqrtf((float)v + 1.0f);  // +1 self-loop
        if ((i & 255) == 0) bcur[i >> 8] = excl;  // bucket cursor seed
        if (i == n - 1) off[n] = etotal;
    }
}

// ---------------- Pass A: LDS-staged bucket binning (256-node buckets) ----------------
// ebuf entry: (dstLocal<<24) | src   (src < 2^24, dstLocal < 256)
#define ACHUNK 2048
#define NBMAX 400
__global__ __launch_bounds__(256) void k_binA(const int* __restrict__ src,
                                              const int* __restrict__ dst,
                                              int* __restrict__ ebuf,
                                              int* __restrict__ bcur,
                                              int e, int nbuck) {
    __shared__ int cnt[NBMAX], startb[NBMAX], posb[NBMAX], gbase[NBMAX];
    __shared__ int stage[ACHUNK];
    __shared__ unsigned short stb[ACHUNK];
    int t = threadIdx.x;
    for (int cbase = blockIdx.x * ACHUNK; cbase < e; cbase += gridDim.x * ACHUNK) {
        int cval = min(ACHUNK, e - cbase);
        for (int i = t; i < nbuck; i += 256) { cnt[i] = 0; posb[i] = 0; }
        __syncthreads();
        int eb[8], es[8];
#pragma unroll
        for (int k = 0; k < 8; ++k) {
            int i = t + k * 256;
            if (i < cval) {
                int s = src[cbase + i];
                int d = dst[cbase + i];
                eb[k] = d >> 8;
                es[k] = s | ((d & 255) << 24);
                atomicAdd(&cnt[eb[k]], 1);
            } else eb[k] = -1;
        }
        __syncthreads();
        if (t == 0) {
            int r = 0;
            for (int b2 = 0; b2 < nbuck; ++b2) { startb[b2] = r; r += cnt[b2]; }
        }
        __syncthreads();
        for (int i = t; i < nbuck; i += 256)
            if (cnt[i] > 0) gbase[i] = atomicAdd(&bcur[i], cnt[i]);
#pragma unroll
        for (int k = 0; k < 8; ++k)
            if (eb[k] >= 0) {
                int idx = startb[eb[k]] + atomicAdd(&posb[eb[k]], 1);
                stage[idx] = es[k];
                stb[idx] = (unsigned short)eb[k];
            }
        __syncthreads();
        for (int i = t; i < cval; i += 256) {
            int b2 = stb[i];
            ebuf[gbase[b2] + (i - startb[b2])] = stage[i];
        }
        __syncthreads();
    }
}

// ---------------- Pass B: within-bucket scatter to CSR (single block per bucket) ----------------
__global__ __launch_bounds__(256) void k_binB(const int* __restrict__ ebuf,
                                              const int* __restrict__ offs,
                                              int* __restrict__ csr, int n) {
    __shared__ int cur[256];
    int b = blockIdx.x;
    int base = b << 8;
    int nn = min(256, n - base);
    int t = threadIdx.x;
    if (t < nn) cur[t] = offs[base + t];
    __syncthreads();
    int e0 = offs[base], e1 = offs[base + nn];
    for (int i = e0 + t; i < e1; i += 256) {
        int packed = ebuf[i];
        int dl = ((unsigned)packed) >> 24;
        int pos = atomicAdd(&cur[dl], 1);
        csr[pos] = packed & 0x00FFFFFF;
    }
}

// ---------------- misc: bounds + mirror mA[i]=dinv*x[i] + zero row N in both mirrors ----------------
__global__ void k_misc(const float* __restrict__ x, const float* __restrict__ dinv,
                       __half* __restrict__ mA, __half* __restrict__ mB, int n,
                       float* __restrict__ gstats,
                       const int* __restrict__ batch, int* __restrict__ bnd, int g) {
    int i = blockIdx.x * 256 + threadIdx.x;
    if (blockIdx.x == 0 && threadIdx.x < 384) gstats[threadIdx.x] = 0.f;
    int total = n * 64;
    if (i < total) {
        mA[i] = __float2half_rn(x[i] * dinv[i >> 6]);
    } else if (i < total + 64) {
        mA[i] = __float2half_rn(0.f);  // dummy zero row at index n (gather tail identity)
        mB[i] = __float2half_rn(0.f);
    }
    if (i < n) {
        int b = batch[i];
        if (i == 0)
            for (int q = 0; q <= b; ++q) bnd[q] = 0;
        else {
            int pb = batch[i - 1];
            for (int q = pb + 1; q <= b; ++q) bnd[q] = i;
        }
        if (i == n - 1)
            for (int q = b + 1; q <= g; ++q) bnd[q] = n;
    }
}

// ---------------- fused: pre-scaled fp16 gather -> row GEMM (fp16 W in LDS) -> BN stats ----------------
// LDS cut to 8 KB (fp16 W tile; stats scratch overlaid after a barrier) to test the
// 64KB-LDS-pool occupancy hypothesis: 18432B -> 3 blocks/CU (obs. 37.5%); 8192B -> 8 blocks/CU.
// agg[d,:] = (dinv[d]*(m16[d,:] + sum_e m16[src_e,:])) @ W + convB,  m16[i]=dinv[i]*h[i]
__global__ __launch_bounds__(256) void k_gather_gemm(const int* __restrict__ off,
                                                     const int* __restrict__ csr,
                                                     const float* __restrict__ dinv,
                                                     const uint4* __restrict__ m16,
                                                     const float* __restrict__ W,
                                                     const float* __restrict__ convB,
                                                     float* __restrict__ agg,
                                                     float* __restrict__ gsum,
                                                     float* __restrict__ gsumsq,
                                                     int n, int nzero) {
    __shared__ __align__(16) __half Wh[64 * 64];  // 8 KB; reused as fp32 stats after loop
    int t = threadIdx.x;
    for (int i = t; i < 64 * 64; i += 256) Wh[i] = __float2half_rn(W[i]);
    int lane = t & 63, wv = t >> 6;
    int oct = lane >> 3;   // which edge of an 8-group this lane gathers
    int sub = lane & 7;    // which 16B chunk (8 cols) of the row
    float bias = convB[lane];
    float s = 0.f, sq = 0.f;
    __syncthreads();
    for (int node = blockIdx.x * 4 + wv; node < n; node += gridDim.x * 4) {
        int a = off[node], b = off[node + 1];
        float dd = dinv[node];
        uint4 vself = m16[(size_t)node * 8 + sub];  // hoisted: in flight during edge loop
        float acc[8];
#pragma unroll
        for (int p = 0; p < 8; ++p) acc[p] = 0.f;
        for (int base = a; base < b; base += 64) {
            int rem = b - base;
            int cnt = rem < 64 ? rem : 64;
            int ent = nzero;  // tail lanes -> dummy zero row (adds 0)
            if (lane < cnt) ent = csr[base + lane];
            for (int jj = 0; jj < cnt; jj += 8) {
                int sn = __shfl(ent, jj + oct, 64);  // jj+oct <= 63 always
                uint4 v = m16[(size_t)sn * 8 + sub];
                const __half2* h2 = reinterpret_cast<const __half2*>(&v);
#pragma unroll
                for (int p = 0; p < 4; ++p) {
                    float2 f = __half22float2(h2[p]);
                    acc[2 * p]     += f.x;
                    acc[2 * p + 1] += f.y;
                }
            }
        }
        // reduce across octs: lanes with equal sub sum up
#pragma unroll
        for (int p = 0; p < 8; ++p) {
            acc[p] += __shfl_xor(acc[p], 8, 64);
            acc[p] += __shfl_xor(acc[p], 16, 64);
            acc[p] += __shfl_xor(acc[p], 32, 64);
        }
        // self term + outer dinv scale (cols 8*sub + p)
        {
            const __half2* h2 = reinterpret_cast<const __half2*>(&vself);
#pragma unroll
            for (int p = 0; p < 4; ++p) {
                float2 f = __half22float2(h2[p]);
                acc[2 * p]     = (acc[2 * p]     + f.x) * dd;
                acc[2 * p + 1] = (acc[2 * p + 1] + f.y) * dd;
            }
        }
        // row GEMM: column c's value is component (c&7) of lane (c>>3)
        float r0 = bias, r1 = 0.f, r2 = 0.f, r3 = 0.f;
#pragma unroll
        for (int c = 0; c < 64; c += 4) {
            r0 += __shfl(acc[(c + 0) & 7], (c + 0) >> 3, 64) * __half2float(Wh[(c + 0) * 64 + lane]);
            r1 += __shfl(acc[(c + 1) & 7], (c + 1) >> 3, 64) * __half2float(Wh[(c + 1) * 64 + lane]);
            r2 += __shfl(acc[(c + 2) & 7], (c + 2) >> 3, 64) * __half2float(Wh[(c + 2) * 64 + lane]);
            r3 += __shfl(acc[(c + 3) & 7], (c + 3) >> 3, 64) * __half2float(Wh[(c + 3) * 64 + lane]);
        }
        float r = (r0 + r1) + (r2 + r3);
        agg[(size_t)node * 64 + lane] = r;
        s += r;
        sq += r * r;
    }
    __syncthreads();  // all waves done reading Wh; overlay stats scratch
    float* ls = (float*)Wh;         // 256 floats
    float* lq = ((float*)Wh) + 256; // 256 floats (total 2 KB << 8 KB)
    ls[t] = s;
    lq[t] = sq;
    __syncthreads();
    if (t < 64) {
        float fs = ls[t] + ls[t + 64] + ls[t + 128] + ls[t + 192];
        float fq = lq[t] + lq[t + 64] + lq[t + 128] + lq[t + 192];
        fatomic_add(&gsum[t], fs);
        fatomic_add(&gsumsq[t], fq);
    }
}

// ---------------- BN + residual(fp16 mirror) + LN + GELU -> fp16 mirror only ----------------
__global__ __launch_bounds__(256) void k_bn_ln_gelu(const float* __restrict__ agg,
                                                    const __half* __restrict__ m16res,
                                                    const float* __restrict__ gsum,
                                                    const float* __restrict__ gsumsq,
                                                    const float* __restrict__ dinv,
                                                    const float* __restrict__ bng,
                                                    const float* __restrict__ bnb,
                                                    const float* __restrict__ lng,
                                                    const float* __restrict__ lnb,
                                                    __half* __restrict__ m16out,
                                                    int n, int has_res, int scale_out) {
    int t = threadIdx.x;
    int lane = t & 63, wv = t >> 6;
    float invN = 1.0f / (float)n;
    float mu_c = gsum[lane] * invN;
    float var_c = gsumsq[lane] * invN - mu_c * mu_c;
    float bscale = rsqrtf(var_c + EPSV) * bng[lane];
    float bshift = bnb[lane];
    float lg = lng[lane], lb = lnb[lane];
    for (int r = blockIdx.x * 4 + wv; r < n; r += gridDim.x * 4) {
        float dd = dinv[r];
        float x = agg[(size_t)r * 64 + lane];
        float hb = (x - mu_c) * bscale + bshift;
        if (has_res) hb += __half2float(m16res[(size_t)r * 64 + lane]) * (1.0f / dd);
        float ssum = hb;
#pragma unroll
        for (int off = 32; off; off >>= 1) ssum += __shfl_xor(ssum, off, 64);
        float rmu = ssum * (1.f / 64.f);
        float d = hb - rmu;
        float vs = d * d;
#pragma unroll
        for (int off = 32; off; off >>= 1) vs += __shfl_xor(vs, off, 64);
        float rvar = vs * (1.f / 64.f);
        float ln = d * rsqrtf(rvar + EPSV) * lg + lb;
        float g = gelu_exact(ln);
        float outv = scale_out ? g * dd : g;
        m16out[(size_t)r * 64 + lane] = __float2half_rn(outv);
    }
}

// ---------------- pooling: one block per graph (4 waves split rows), fp16 h ----------------
__global__ __launch_bounds__(256) void k_pool_z(const __half* __restrict__ h,
                                                const int* __restrict__ bnd,
                                                float* __restrict__ z) {
    int g = blockIdx.x;
    int t = threadIdx.x;
    int lane = t & 63, wv = t >> 6;
    int s0 = bnd[g], e0 = bnd[g + 1];
    float s = 0.f, mx = -INFINITY;
    for (int i = s0 + wv; i < e0; i += 4) {
        float v = __half2float(h[(size_t)i * 64 + lane]);
        s += v;
        mx = fmaxf(mx, v);
    }
    __shared__ float ss[256], sm[256];
    ss[t] = s;
    sm[t] = mx;
    __syncthreads();
    if (t < 64) {
        float fs = ss[t] + ss[t + 64] + ss[t + 128] + ss[t + 192];
        float fm = fmaxf(fmaxf(sm[t], sm[t + 64]), fmaxf(sm[t + 128], sm[t + 192]));
        float cntf = (float)(e0 - s0);
        float mean = fs / fmaxf(cntf, 1.0f);
        if (e0 == s0) fm = 0.f;
        z[g * 192 + t] = mean;
        z[g * 192 + 64 + t] = fm;
        z[g * 192 + 128 + t] = fs;
    }
}

// ---------------- MLP head (one block per graph) ----------------
__global__ __launch_bounds__(128) void k_head(const float* __restrict__ z,
                                              const float* __restrict__ W1, const float* __restrict__ b1,
                                              const float* __restrict__ ln1g, const float* __restrict__ ln1b,
                                              const float* __restrict__ W2, const float* __restrict__ b2,
                                              const float* __restrict__ ln2g, const float* __restrict__ ln2b,
                                              const float* __restrict__ W3, const float* __restrict__ b3,
                                              float* __restrict__ out) {
    int g = blockIdx.x;
    int t = threadIdx.x;
    int lane = t & 63, wv = t >> 6;
    __shared__ float zl[192], h1[128], red[2];
    for (int i = t; i < 192; i += 128) zl[i] = z[g * 192 + i];
    __syncthreads();
    float acc = b1[t];
    for (int k = 0; k < 192; ++k) acc += zl[k] * W1[k * 128 + t];
    float s = acc;
#pragma unroll
    for (int off = 32; off; off >>= 1) s += __shfl_xor(s, off, 64);
    if (lane == 0) red[wv] = s;
    __syncthreads();
    float mu = (red[0] + red[1]) * (1.f / 128.f);
    float d = acc - mu;
    float q = d * d;
#pragma unroll
    for (int off = 32; off; off >>= 1) q += __shfl_xor(q, off, 64);
    __syncthreads();
    if (lane == 0) red[wv] = q;
    __syncthreads();
    float var = (red[0] + red[1]) * (1.f / 128.f);
    float ln = d * rsqrtf(var + EPSV) * ln1g[t] + ln1b[t];
    h1[t] = gelu_exact(ln);
    __syncthreads();
    if (t < 64) {
        float acc2 = b2[t];
        for (int k = 0; k < 128; ++k) acc2 += h1[k] * W2[k * 64 + t];
        float s2 = acc2;
#pragma unroll
        for (int off = 32; off; off >>= 1) s2 += __shfl_xor(s2, off, 64);
        float mu2 = s2 * (1.f / 64.f);
        float d2 = acc2 - mu2;
        float q2 = d2 * d2;
#pragma unroll
        for (int off = 32; off; off >>= 1) q2 += __shfl_xor(q2, off, 64);
        float var2 = q2 * (1.f / 64.f);
        float l2 = d2 * rsqrtf(var2 + EPSV) * ln2g[t] + ln2b[t];
        float g2 = gelu_exact(l2);
        float p = g2 * W3[t];
#pragma unroll
        for (int off = 32; off; off >>= 1) p += __shfl_xor(p, off, 64);
        if (t == 0) out[g] = p + b3[0];
    }
}

extern "C" void kernel_launch(void* const* d_in, const int* in_sizes, int n_in,
                              void* d_out, int out_size, void* d_ws, size_t ws_size,
                              hipStream_t stream) {
    const float* x      = (const float*)d_in[0];
    const int*   eidx   = (const int*)d_in[1];
    const int*   batch  = (const int*)d_in[2];
    const float* convW  = (const float*)d_in[3];
    const float* convB  = (const float*)d_in[4];
    const float* bn_g   = (const float*)d_in[5];
    const float* bn_b   = (const float*)d_in[6];
    const float* ln_g   = (const float*)d_in[7];
    const float* ln_b   = (const float*)d_in[8];
    const float* W1     = (const float*)d_in[9];
    const float* b1     = (const float*)d_in[10];
    const float* ln1g   = (const float*)d_in[11];
    const float* ln1b   = (const float*)d_in[12];
    const float* W2     = (const float*)d_in[13];
    const float* b2     = (const float*)d_in[14];
    const float* ln2g   = (const float*)d_in[15];
    const float* ln2b   = (const float*)d_in[16];
    const float* W3     = (const float*)d_in[17];
    const float* b3     = (const float*)d_in[18];
    float* out = (float*)d_out;

    const int N = in_sizes[0] / DD;
    const int E = in_sizes[1] / 2;
    const int G = out_size;
    const int* esrc = eidx;
    const int* edst = eidx + E;

    char* ws = (char*)d_ws;
    size_t off_b = 0;
    auto alloc = [&](size_t bytes) {
        size_t p = off_b;
        off_b = (off_b + bytes + 255) & ~(size_t)255;
        return (void*)(ws + p);
    };
    // layout total ~65 MB (< 77.6 MB proven safe):
    int*    offs   = (int*)alloc((size_t)(N + 1) * 4);
    float*  dinv   = (float*)alloc((size_t)N * 4);
    int*    csr    = (int*)alloc((size_t)E * 4);                 // src only
    int*    ebuf   = (int*)alloc((size_t)E * 4);                 // bucket-grouped packed edges
    __half* m16A   = (__half*)alloc((size_t)(N + 1) * DD * 2);   // +1 dummy zero row
    __half* m16B   = (__half*)alloc((size_t)(N + 1) * DD * 2);
    float*  aggbuf = (float*)alloc((size_t)N * DD * 4);          // single fp32 agg buffer
    float*  gstats = (float*)alloc(3 * 2 * DD * 4);              // 3 layers x (gsum|gsumsq)
    int*    bnd    = (int*)alloc((size_t)(G + 1) * 4);
    int*    bsum   = (int*)alloc(((size_t)(N + 1023) / 1024) * 4);
    int*    bcur   = (int*)alloc(((size_t)(N + 255) / 256) * 4);
    // aliases into dead regions of aggbuf:
    int*   counts = (int*)aggbuf;  // live only during CSR build (before L0 gather)
    float* z      = aggbuf;        // live only after L2 bn consumed aggbuf
    (void)ws_size; (void)n_in;

    const int nb = (N + 1023) / 1024;
    const int nbuck = (N + 255) / 256;

    // ---- CSR build (once per launch): hist -> scan -> two-pass binned fill ----
    hipMemsetAsync(counts, 0, (size_t)N * 4, stream);
    k_hist<<<(E + 255) / 256, 256, 0, stream>>>(edst, counts, E);
    k_bsum<<<nb, 1024, 0, stream>>>(counts, bsum, N);
    k_bscan<<<1, 128, 0, stream>>>(bsum, nb);
    k_downsweep<<<nb, 1024, 0, stream>>>(counts, bsum, offs, dinv, bcur, N, E);
    k_binA<<<(E + ACHUNK - 1) / ACHUNK, 256, 0, stream>>>(esrc, edst, ebuf, bcur, E, nbuck);
    k_binB<<<nbuck, 256, 0, stream>>>(ebuf, offs, csr, N);
    k_misc<<<((N + 1) * DD + 255) / 256, 256, 0, stream>>>(x, dinv, m16A, m16B, N, gstats, batch, bnd, G);

    // mirror rotation:
    //   L0: gather m16A -> agg; bn: agg -> m16B (scaled)          [res: none]
    //   L1: gather m16B -> agg; bn: agg + res(m16B) -> m16A (scaled)
    //   L2: gather m16A -> agg; bn: agg + res(m16A) -> m16B (unscaled, feeds pool)
    __half* gin[3]  = {m16A, m16B, m16A};
    __half* gout[3] = {m16B, m16A, m16B};

    for (int l = 0; l < 3; ++l) {
        float* gsum = gstats + l * 128;
        float* gsumsq = gsum + 64;
        k_gather_gemm<<<2048, 256, 0, stream>>>(offs, csr, dinv, (const uint4*)gin[l],
                                                convW + (size_t)l * DD * DD, convB + l * DD,
                                                aggbuf, gsum, gsumsq, N, N);
        k_bn_ln_gelu<<<2048, 256, 0, stream>>>(aggbuf, gin[l], gsum, gsumsq, dinv,
                                               bn_g + l * DD, bn_b + l * DD,
                                               ln_g + l * DD, ln_b + l * DD,
                                               gout[l], N, l > 0 ? 1 : 0, l < 2 ? 1 : 0);
    }

    k_pool_z<<<G, 256, 0, stream>>>(m16B, bnd, z);
    k_head<<<G, 128, 0, stream>>>(z, W1, b1, ln1g, ln1b, W2, b2, ln2g, ln2b, W3, b3, out);
}